// Round 1
// baseline (465.738 us; speedup 1.0000x reference)
//
#include <hip/hip_runtime.h>
#include <math.h>

// out[b,t,d] = x[b,t,d] + pe[t,d]
// pe[t,d] = (d even) ? sin(t * 10000^(-2d/1024)) : cos(t * 10000^(-2d/1024))
//
// Shapes: x [32, 2048, 1024] fp32, out same. Pure memory-bound add with a
// broadcast positional-encoding term. Each thread owns one float4 of (t,d)
// (d0 = 4*k, so the sin/cos parity pattern within the vector is fixed:
// sin,cos,sin,cos) and loops over the 32 batch slices, so the 8
// transcendentals per thread amortize over 128 elements.

constexpr int D_MODEL = 1024;
constexpr int T_STEPS = 2048;
constexpr int BATCH   = 32;

__global__ __launch_bounds__(256) void pe_add_kernel(const float* __restrict__ x,
                                                     float* __restrict__ out) {
    // One thread per float4 of the [T, D] plane.
    const int idx = blockIdx.x * blockDim.x + threadIdx.x;   // 0 .. T*D/4 - 1
    const int d4  = idx & (D_MODEL / 4 - 1);                 // which float4 in the row
    const int t   = idx >> 8;                                // D/4 == 256
    const int d0  = d4 * 4;

    const float pos = (float)t;
    // 2*log2(10000)/1024
    const float c = 0.025952563241307517f;

    float4 pe;
    {
        const float a0 = pos * __builtin_exp2f(-(float)(d0 + 0) * c);
        const float a1 = pos * __builtin_exp2f(-(float)(d0 + 1) * c);
        const float a2 = pos * __builtin_exp2f(-(float)(d0 + 2) * c);
        const float a3 = pos * __builtin_exp2f(-(float)(d0 + 3) * c);
        pe.x = sinf(a0);   // d even -> sin
        pe.y = cosf(a1);   // d odd  -> cos
        pe.z = sinf(a2);
        pe.w = cosf(a3);
    }

    const float4* __restrict__ xv = (const float4*)x;
    float4* __restrict__ ov       = (float4*)out;

    const size_t stride4 = (size_t)T_STEPS * D_MODEL / 4;    // one batch slice, in float4s
    size_t p = (size_t)t * (D_MODEL / 4) + d4;

#pragma unroll 8
    for (int b = 0; b < BATCH; ++b) {
        float4 v = xv[p];
        v.x += pe.x;
        v.y += pe.y;
        v.z += pe.z;
        v.w += pe.w;
        ov[p] = v;
        p += stride4;
    }
}

extern "C" void kernel_launch(void* const* d_in, const int* in_sizes, int n_in,
                              void* d_out, int out_size, void* d_ws, size_t ws_size,
                              hipStream_t stream) {
    const float* x = (const float*)d_in[0];
    float* out     = (float*)d_out;

    const int threads_total = T_STEPS * D_MODEL / 4;         // 524288
    const int block = 256;
    const int grid  = threads_total / block;                 // 2048

    pe_add_kernel<<<grid, block, 0, stream>>>(x, out);
}

// Round 2
// 419.023 us; speedup vs baseline: 1.1115x; 1.1115x over previous
//
#include <hip/hip_runtime.h>
#include <math.h>

// out[b,t,d] = x[b,t,d] + pe[t,d]
// pe[t,d] = (d even) ? sin(t * 10000^(-2d/1024)) : cos(t * 10000^(-2d/1024))
//
// R2 structure: two kernels.
//   1) pe_build: compute pe[2048,1024] (8 MB fp32) into d_ws. Tiny (trig off
//      the hot path).
//   2) pe_add_stream: one float4 per thread over the whole [32,2048,1024]
//      tensor, out[i] = x[i] + pe[i & (T*D-1)]. This matches the measured
//      6.29 TB/s float4-copy structure (single load->add->store, no
//      load/store vmcnt coupling across loop iterations, 65536 blocks of
//      wave churn instead of one exact machine-fill).
// R1's batch-loop RMW kernel ran at only ~3 TB/s (175 us); kept as fallback
// if ws_size is too small for pe.

constexpr int D_MODEL = 1024;
constexpr int T_STEPS = 2048;
constexpr int BATCH   = 32;
constexpr int TD4     = T_STEPS * D_MODEL / 4;   // float4s per [T,D] plane = 524288

__global__ __launch_bounds__(256) void pe_build_kernel(float* __restrict__ pe_out) {
    const int idx = blockIdx.x * blockDim.x + threadIdx.x;   // 0 .. TD4-1
    const int d4  = idx & (D_MODEL / 4 - 1);
    const int t   = idx >> 8;                                // D/4 == 256
    const int d0  = d4 * 4;

    const float pos = (float)t;
    const float c = 0.025952563241307517f;                   // 2*log2(10000)/1024

    float4 pe;
    pe.x = sinf(pos * __builtin_exp2f(-(float)(d0 + 0) * c));  // even d -> sin
    pe.y = cosf(pos * __builtin_exp2f(-(float)(d0 + 1) * c));  // odd d  -> cos
    pe.z = sinf(pos * __builtin_exp2f(-(float)(d0 + 2) * c));
    pe.w = cosf(pos * __builtin_exp2f(-(float)(d0 + 3) * c));

    ((float4*)pe_out)[idx] = pe;
}

__global__ __launch_bounds__(256) void pe_add_stream_kernel(const float* __restrict__ x,
                                                            const float* __restrict__ pe,
                                                            float* __restrict__ out) {
    const int idx = blockIdx.x * blockDim.x + threadIdx.x;   // 0 .. B*TD4-1
    const int j   = idx & (TD4 - 1);                         // pe float4 index

    float4 v = ((const float4*)x)[idx];
    const float4 p = ((const float4*)pe)[j];
    v.x += p.x;
    v.y += p.y;
    v.z += p.z;
    v.w += p.w;
    ((float4*)out)[idx] = v;
}

// Fallback (R1): in-register pe, batch loop. ~3 TB/s but needs no workspace.
__global__ __launch_bounds__(256) void pe_add_loop_kernel(const float* __restrict__ x,
                                                          float* __restrict__ out) {
    const int idx = blockIdx.x * blockDim.x + threadIdx.x;
    const int d4  = idx & (D_MODEL / 4 - 1);
    const int t   = idx >> 8;
    const int d0  = d4 * 4;

    const float pos = (float)t;
    const float c = 0.025952563241307517f;

    float4 pe;
    pe.x = sinf(pos * __builtin_exp2f(-(float)(d0 + 0) * c));
    pe.y = cosf(pos * __builtin_exp2f(-(float)(d0 + 1) * c));
    pe.z = sinf(pos * __builtin_exp2f(-(float)(d0 + 2) * c));
    pe.w = cosf(pos * __builtin_exp2f(-(float)(d0 + 3) * c));

    const float4* __restrict__ xv = (const float4*)x;
    float4* __restrict__ ov       = (float4*)out;
    size_t p = (size_t)t * (D_MODEL / 4) + d4;

    for (int b = 0; b < BATCH; ++b) {
        float4 v = xv[p];
        v.x += pe.x; v.y += pe.y; v.z += pe.z; v.w += pe.w;
        ov[p] = v;
        p += (size_t)TD4;
    }
}

extern "C" void kernel_launch(void* const* d_in, const int* in_sizes, int n_in,
                              void* d_out, int out_size, void* d_ws, size_t ws_size,
                              hipStream_t stream) {
    const float* x = (const float*)d_in[0];
    float* out     = (float*)d_out;

    const size_t pe_bytes = (size_t)T_STEPS * D_MODEL * sizeof(float);  // 8 MiB

    if (d_ws != nullptr && ws_size >= pe_bytes) {
        float* pe = (float*)d_ws;
        pe_build_kernel<<<TD4 / 256, 256, 0, stream>>>(pe);
        const int total4 = BATCH * TD4;                       // 16777216
        pe_add_stream_kernel<<<total4 / 256, 256, 0, stream>>>(x, pe, out);
    } else {
        pe_add_loop_kernel<<<TD4 / 256, 256, 0, stream>>>(x, out);
    }
}